// Round 1
// baseline (440.522 us; speedup 1.0000x reference)
//
#include <hip/hip_runtime.h>
#include <hip/hip_bf16.h>
#include <math.h>

// Problem constants (from reference)
#define D_SVG 256
#define N_TYPE 10
#define N_PAR 12
#define F_TOT (D_SVG + N_TYPE + N_PAR)   // 278
#define ROWS_PER_BLOCK 32
#define THREADS 256

// ws layout: acc[0]=svg_sq_sum, acc[1]=par_sq_sum, acc[2]=nll_sum, acc[3]=valid_count

__global__ __launch_bounds__(THREADS) void loss_main(const float* __restrict__ input,
                                                     const float* __restrict__ target,
                                                     double* __restrict__ acc,
                                                     int nrows) {
    __shared__ unsigned smeta[ROWS_PER_BLOCK];   // bit31 = valid, bits 0..11 = pmask
    __shared__ float sred[4][4];                 // 4 waves x 4 partials

    const int tid = threadIdx.x;
    const long row0 = (long)blockIdx.x * ROWS_PER_BLOCK;

    float nll_acc = 0.0f;
    float cnt_acc = 0.0f;

    // --- per-row metadata + cross-entropy (threads 0..31, one row each) ---
    if (tid < ROWS_PER_BLOCK) {
        unsigned meta = 0u;
        long r = row0 + tid;
        if (r < nrows) {
            long b = r * F_TOT + D_SVG;          // start of type section
            float t0 = target[b];
            if (t0 != -1.0f) {                   // valid (non-padded) row
                // argmax of one-hot target type + gather input logits
                int ti = 0;
                float best = t0;
                float l[N_TYPE];
                #pragma unroll
                for (int j = 0; j < N_TYPE; ++j) {
                    float tv = target[b + j];
                    if (tv > best) { best = tv; ti = j; }
                    l[j] = input[b + j];         // valid rows: input unmodified
                }
                float m = l[0];
                #pragma unroll
                for (int j = 1; j < N_TYPE; ++j) m = fmaxf(m, l[j]);
                float s = 0.0f;
                #pragma unroll
                for (int j = 0; j < N_TYPE; ++j) s += __expf(l[j] - m);
                nll_acc = __logf(s) + m - l[ti];
                cnt_acc = 1.0f;
                // PARAM_MASK[t] = bits {t, t+1, t+2}; t<=9 so no mod-12 wrap
                meta = 0x80000000u | (7u << ti);
            }
        }
        smeta[tid] = meta;
    }
    __syncthreads();

    // --- bulk MSE over the 32-row chunk, coalesced float4 ---
    float svg_acc = 0.0f, par_acc = 0.0f;
    const int n4 = (ROWS_PER_BLOCK * F_TOT) / 4;           // 2224 float4 per chunk
    const float4* __restrict__ in4p = (const float4*)(input + row0 * F_TOT);
    const float4* __restrict__ tg4p = (const float4*)(target + row0 * F_TOT);

    for (int idx = tid; idx < n4; idx += THREADS) {
        float4 iv = in4p[idx];
        float4 tv = tg4p[idx];
        float vi[4] = {iv.x, iv.y, iv.z, iv.w};
        float vt[4] = {tv.x, tv.y, tv.z, tv.w};

        int e0 = idx * 4;                // local element index
        int row_l = e0 / F_TOT;          // magic-mul division by 278
        int feat = e0 - row_l * F_TOT;
        unsigned meta = smeta[row_l];

        #pragma unroll
        for (int j = 0; j < 4; ++j) {
            if (feat == F_TOT) { feat = 0; ++row_l; meta = smeta[row_l]; }
            float x = (meta & 0x80000000u) ? vi[j] : -100.0f;   // padded -> -100
            if (feat < D_SVG) {
                float d = x - vt[j];
                svg_acc = fmaf(d, d, svg_acc);
            } else if (feat >= D_SVG + N_TYPE) {
                int k = feat - (D_SVG + N_TYPE);
                if (!((meta >> k) & 1u)) {        // not replaced by target param
                    float d = x - vt[j];
                    par_acc = fmaf(d, d, par_acc);
                }
                // replaced -> in_par == tg_par -> contributes 0
            }
            // feat in [256,266): type logits, handled by CE above
            ++feat;
        }
    }

    // --- block reduction: wave shuffle then LDS across 4 waves ---
    float vals[4] = {svg_acc, par_acc, nll_acc, cnt_acc};
    #pragma unroll
    for (int v = 0; v < 4; ++v) {
        float x = vals[v];
        #pragma unroll
        for (int off = 32; off > 0; off >>= 1) x += __shfl_down(x, off, 64);
        vals[v] = x;
    }
    const int wave = tid >> 6;
    const int lane = tid & 63;
    if (lane == 0) {
        #pragma unroll
        for (int v = 0; v < 4; ++v) sred[wave][v] = vals[v];
    }
    __syncthreads();
    if (tid == 0) {
        #pragma unroll
        for (int v = 0; v < 4; ++v) {
            float t = sred[0][v] + sred[1][v] + sred[2][v] + sred[3][v];
            atomicAdd(&acc[v], (double)t);
        }
    }
}

__global__ void loss_final(const double* __restrict__ acc, float* __restrict__ out,
                           double inv_svg_n, double inv_par_n) {
    double svg = acc[0], par = acc[1], nll = acc[2], cnt = acc[3];
    double loss = 10.0 * svg * inv_svg_n
                + 0.1 * nll / fmax(cnt, 1.0)
                + 1.0 * par * inv_par_n;
    out[0] = (float)loss;
}

extern "C" void kernel_launch(void* const* d_in, const int* in_sizes, int n_in,
                              void* d_out, int out_size, void* d_ws, size_t ws_size,
                              hipStream_t stream) {
    const float* input  = (const float*)d_in[0];
    const float* target = (const float*)d_in[1];
    // d_in[2] (padding mask) is unused: padded <=> target[row*278+256] == -1.0f
    float*  out = (float*)d_out;
    double* acc = (double*)d_ws;

    const int nrows = in_sizes[0] / F_TOT;      // B*S = 131072
    const int blocks = (nrows + ROWS_PER_BLOCK - 1) / ROWS_PER_BLOCK;

    hipMemsetAsync(d_ws, 0, 4 * sizeof(double), stream);
    loss_main<<<blocks, THREADS, 0, stream>>>(input, target, acc, nrows);
    loss_final<<<1, 1, 0, stream>>>(acc, out,
                                    1.0 / ((double)nrows * D_SVG),
                                    1.0 / ((double)nrows * N_PAR));
}

// Round 2
// 321.282 us; speedup vs baseline: 1.3711x; 1.3711x over previous
//
#include <hip/hip_runtime.h>
#include <hip/hip_bf16.h>
#include <math.h>

// Problem constants (from reference)
#define D_SVG 256
#define N_TYPE 10
#define N_PAR 12
#define F_TOT (D_SVG + N_TYPE + N_PAR)        // 278
#define ROWS_PER_BLOCK 32
#define THREADS 256
#define N4_PER_BLOCK (ROWS_PER_BLOCK * F_TOT / 4)   // 2224 float4 per chunk
#define FULL_ITERS (N4_PER_BLOCK / THREADS)         // 8
#define TAIL (N4_PER_BLOCK - FULL_ITERS * THREADS)  // 176

// d_ws layout: float4 part[nblocks]  (x=svg_sq, y=par_sq, z=nll, w=valid_cnt)

__global__ __launch_bounds__(THREADS) void loss_main(const float* __restrict__ input,
                                                     const float* __restrict__ target,
                                                     float4* __restrict__ part,
                                                     int nrows) {
    __shared__ unsigned smeta[ROWS_PER_BLOCK];   // bit31 = valid, bits 0..11 = pmask
    __shared__ float sred[4][4];                 // 4 waves x 4 partials

    const int tid = threadIdx.x;
    const long row0 = (long)blockIdx.x * ROWS_PER_BLOCK;

    float nll_acc = 0.0f;
    float cnt_acc = 0.0f;

    // --- per-row metadata + cross-entropy (threads 0..31, one row each) ---
    if (tid < ROWS_PER_BLOCK) {
        unsigned meta = 0u;
        long r = row0 + tid;
        if (r < nrows) {
            long b = r * F_TOT + D_SVG;          // start of type section
            float t0 = target[b];
            if (t0 != -1.0f) {                   // valid (non-padded) row
                int ti = 0;
                float best = t0;
                float l[N_TYPE];
                #pragma unroll
                for (int j = 0; j < N_TYPE; ++j) {
                    float tv = target[b + j];
                    if (tv > best) { best = tv; ti = j; }
                    l[j] = input[b + j];         // valid rows: input unmodified
                }
                float m = l[0];
                #pragma unroll
                for (int j = 1; j < N_TYPE; ++j) m = fmaxf(m, l[j]);
                float s = 0.0f;
                #pragma unroll
                for (int j = 0; j < N_TYPE; ++j) s += __expf(l[j] - m);
                nll_acc = __logf(s) + m - l[ti];
                cnt_acc = 1.0f;
                // PARAM_MASK[t] = bits {t, t+1, t+2}; t<=9 so no mod-12 wrap
                meta = 0x80000000u | (7u << ti);
            }
        }
        smeta[tid] = meta;
    }
    __syncthreads();

    // --- bulk MSE over the 32-row chunk, coalesced float4, branch-free ---
    float svg_acc = 0.0f, par_acc = 0.0f;
    const float4* __restrict__ in4p = (const float4*)(input + row0 * F_TOT);
    const float4* __restrict__ tg4p = (const float4*)(target + row0 * F_TOT);

    // 278 % 4 == 2, so a float4 crosses a row boundary only between elems 1|2:
    // elems {0,1} belong to row(e0), elems {2,3} to row(e0+2).
    auto body = [&](int idx) {
        float4 iv = in4p[idx];
        float4 tv = tg4p[idx];
        unsigned e0 = (unsigned)idx * 4u;
        unsigned ra = e0 / (unsigned)F_TOT;            // compiler magic-mul
        unsigned rb = (e0 + 2u) / (unsigned)F_TOT;
        unsigned fa = e0 - ra * (unsigned)F_TOT;
        unsigned fb = (e0 + 2u) - rb * (unsigned)F_TOT;
        unsigned ma = smeta[ra];                       // broadcast within wave
        unsigned mb = smeta[rb];
        float xs[4] = {iv.x, iv.y, iv.z, iv.w};
        float ts[4] = {tv.x, tv.y, tv.z, tv.w};
        #pragma unroll
        for (int j = 0; j < 4; ++j) {
            unsigned meta = (j < 2) ? ma : mb;
            unsigned feat = ((j < 2) ? fa : fb) + (unsigned)(j & 1);
            float x = (meta & 0x80000000u) ? xs[j] : -100.0f;   // padded -> -100
            float d = x - ts[j];
            float sq = d * d;
            if (feat < D_SVG) {
                svg_acc += sq;
            } else if (feat >= D_SVG + N_TYPE) {
                unsigned k = feat - (D_SVG + N_TYPE);
                par_acc += ((meta >> k) & 1u) ? 0.0f : sq;  // replaced -> 0
            }
        }
    };

    #pragma unroll
    for (int u = 0; u < FULL_ITERS; ++u) body(tid + u * THREADS);
    if (tid < TAIL) body(FULL_ITERS * THREADS + tid);

    // --- block reduction: wave shuffle then LDS across 4 waves ---
    float vals[4] = {svg_acc, par_acc, nll_acc, cnt_acc};
    #pragma unroll
    for (int v = 0; v < 4; ++v) {
        float x = vals[v];
        #pragma unroll
        for (int off = 32; off > 0; off >>= 1) x += __shfl_down(x, off, 64);
        vals[v] = x;
    }
    const int wave = tid >> 6;
    const int lane = tid & 63;
    if (lane == 0) {
        #pragma unroll
        for (int v = 0; v < 4; ++v) sred[wave][v] = vals[v];
    }
    __syncthreads();
    if (tid == 0) {
        float s0 = sred[0][0] + sred[1][0] + sred[2][0] + sred[3][0];
        float s1 = sred[0][1] + sred[1][1] + sred[2][1] + sred[3][1];
        float s2 = sred[0][2] + sred[1][2] + sred[2][2] + sred[3][2];
        float s3 = sred[0][3] + sred[1][3] + sred[2][3] + sred[3][3];
        part[blockIdx.x] = make_float4(s0, s1, s2, s3);
    }
}

__global__ __launch_bounds__(256) void loss_reduce(const float4* __restrict__ part,
                                                   float* __restrict__ out, int nblocks,
                                                   double inv_svg_n, double inv_par_n) {
    __shared__ double sred[4][4];
    const int tid = threadIdx.x;
    double sv = 0.0, pa = 0.0, nl = 0.0, ct = 0.0;
    for (int i = tid; i < nblocks; i += 256) {
        float4 v = part[i];
        sv += v.x; pa += v.y; nl += v.z; ct += v.w;
    }
    double vals[4] = {sv, pa, nl, ct};
    #pragma unroll
    for (int v = 0; v < 4; ++v) {
        double x = vals[v];
        #pragma unroll
        for (int off = 32; off > 0; off >>= 1) x += __shfl_down(x, off, 64);
        vals[v] = x;
    }
    const int wave = tid >> 6;
    const int lane = tid & 63;
    if (lane == 0) {
        #pragma unroll
        for (int v = 0; v < 4; ++v) sred[wave][v] = vals[v];
    }
    __syncthreads();
    if (tid == 0) {
        double svg = sred[0][0] + sred[1][0] + sred[2][0] + sred[3][0];
        double par = sred[0][1] + sred[1][1] + sred[2][1] + sred[3][1];
        double nll = sred[0][2] + sred[1][2] + sred[2][2] + sred[3][2];
        double cnt = sred[0][3] + sred[1][3] + sred[2][3] + sred[3][3];
        double loss = 10.0 * svg * inv_svg_n
                    + 0.1 * nll / fmax(cnt, 1.0)
                    + 1.0 * par * inv_par_n;
        out[0] = (float)loss;
    }
}

extern "C" void kernel_launch(void* const* d_in, const int* in_sizes, int n_in,
                              void* d_out, int out_size, void* d_ws, size_t ws_size,
                              hipStream_t stream) {
    const float* input  = (const float*)d_in[0];
    const float* target = (const float*)d_in[1];
    // d_in[2] (padding mask) unused: padded <=> target[row*278+256] == -1.0f
    float*  out  = (float*)d_out;
    float4* part = (float4*)d_ws;

    const int nrows = in_sizes[0] / F_TOT;      // B*S = 131072
    const int blocks = (nrows + ROWS_PER_BLOCK - 1) / ROWS_PER_BLOCK;  // 4096

    loss_main<<<blocks, THREADS, 0, stream>>>(input, target, part, nrows);
    loss_reduce<<<1, 256, 0, stream>>>(part, out, blocks,
                                       1.0 / ((double)nrows * D_SVG),
                                       1.0 / ((double)nrows * N_PAR));
}

// Round 3
// 316.925 us; speedup vs baseline: 1.3900x; 1.0137x over previous
//
#include <hip/hip_runtime.h>
#include <hip/hip_bf16.h>
#include <math.h>

// Problem constants (from reference)
#define D_SVG 256
#define N_TYPE 10
#define N_PAR 12
#define F_TOT (D_SVG + N_TYPE + N_PAR)        // 278
#define ROWS_PER_BLOCK 32
#define THREADS 256
#define N4_PER_BLOCK (ROWS_PER_BLOCK * F_TOT / 4)   // 2224 float4 per chunk
#define FULL_ITERS (N4_PER_BLOCK / THREADS)         // 8
#define TAIL (N4_PER_BLOCK - FULL_ITERS * THREADS)  // 176

// Padded-row closed form: input forced to -100, target == -1 everywhere, CE skipped.
// Per row: svg += 256*(-99)^2, par += 12*(-99)^2.  9801*8192 and 9801*384 are
// exactly representable in fp32 (9801 = 14-bit mantissa * pow2).
#define PAD_SVG_BLOCK (9801.0f * D_SVG * ROWS_PER_BLOCK)
#define PAD_PAR_BLOCK (9801.0f * N_PAR * ROWS_PER_BLOCK)

// d_ws layout: float4 part[nblocks]  (x=svg_sq, y=par_sq, z=nll, w=valid_cnt)

__global__ __launch_bounds__(THREADS) void loss_main(const float* __restrict__ input,
                                                     const float* __restrict__ target,
                                                     float4* __restrict__ part,
                                                     int nrows) {
    __shared__ unsigned smeta[ROWS_PER_BLOCK];   // bit31 = valid, bits 0..11 = pmask
    __shared__ unsigned long long sballot;       // valid-row ballot (wave 0)
    __shared__ float sred[4][4];                 // 4 waves x 4 partials

    const int tid = threadIdx.x;
    const long row0 = (long)blockIdx.x * ROWS_PER_BLOCK;

    float nll_acc = 0.0f;
    float cnt_acc = 0.0f;

    // --- per-row metadata + cross-entropy (threads 0..31 of wave 0, one row each) ---
    if (tid < ROWS_PER_BLOCK) {
        unsigned meta = 0u;
        long r = row0 + tid;            // nrows % 32 == 0, always in range
        long b2 = (r * F_TOT + D_SVG) >> 1;      // float2 index of type section (even)
        const float2* __restrict__ tg2 = (const float2*)target;
        const float2* __restrict__ in2 = (const float2*)input;
        float2 t01 = tg2[b2];
        if (t01.x != -1.0f) {                    // valid (non-padded) row
            float tg[N_TYPE], l[N_TYPE];
            tg[0] = t01.x; tg[1] = t01.y;
            #pragma unroll
            for (int j = 1; j < 5; ++j) { float2 v = tg2[b2 + j]; tg[2*j] = v.x; tg[2*j+1] = v.y; }
            #pragma unroll
            for (int j = 0; j < 5; ++j) { float2 v = in2[b2 + j]; l[2*j] = v.x; l[2*j+1] = v.y; }
            int ti = 0; float best = tg[0];
            #pragma unroll
            for (int j = 1; j < N_TYPE; ++j) { if (tg[j] > best) { best = tg[j]; ti = j; } }
            float m = l[0];
            #pragma unroll
            for (int j = 1; j < N_TYPE; ++j) m = fmaxf(m, l[j]);
            float s = 0.0f;
            #pragma unroll
            for (int j = 0; j < N_TYPE; ++j) s += __expf(l[j] - m);
            nll_acc = __logf(s) + m - l[ti];
            cnt_acc = 1.0f;
            // PARAM_MASK[t] = bits {t, t+1, t+2}; t<=9 so no mod-12 wrap
            meta = 0x80000000u | (7u << ti);
        }
        smeta[tid] = meta;
        unsigned long long bal = __ballot(meta != 0u);   // lanes 0..31 of wave 0
        if (tid == 0) sballot = bal;
    }
    __syncthreads();

    // --- all 32 rows padded: closed-form contribution, skip the 35 KB chunk ---
    if (sballot == 0ull) {
        if (tid == 0) part[blockIdx.x] = make_float4(PAD_SVG_BLOCK, PAD_PAR_BLOCK, 0.0f, 0.0f);
        return;
    }

    // --- bulk MSE over the 32-row chunk: batch ALL loads first (16 in flight) ---
    float svg_acc = 0.0f, par_acc = 0.0f;
    const float4* __restrict__ in4p = (const float4*)(input + row0 * F_TOT);
    const float4* __restrict__ tg4p = (const float4*)(target + row0 * F_TOT);

    float4 iv[FULL_ITERS], tv[FULL_ITERS];
    #pragma unroll
    for (int u = 0; u < FULL_ITERS; ++u) iv[u] = in4p[tid + u * THREADS];
    #pragma unroll
    for (int u = 0; u < FULL_ITERS; ++u) tv[u] = tg4p[tid + u * THREADS];

    // 278 % 4 == 2: a float4 crosses a row boundary only between elems 1|2.
    auto accum = [&](int idx, float4 ivv, float4 tvv) {
        unsigned e0 = (unsigned)idx * 4u;
        unsigned ra = e0 / (unsigned)F_TOT;            // compiler magic-mul
        unsigned rb = (e0 + 2u) / (unsigned)F_TOT;
        unsigned fa = e0 - ra * (unsigned)F_TOT;
        unsigned fb = (e0 + 2u) - rb * (unsigned)F_TOT;
        unsigned ma = smeta[ra];                       // LDS broadcast
        unsigned mb = smeta[rb];
        float xs[4] = {ivv.x, ivv.y, ivv.z, ivv.w};
        float ts[4] = {tvv.x, tvv.y, tvv.z, tvv.w};
        #pragma unroll
        for (int j = 0; j < 4; ++j) {
            unsigned meta = (j < 2) ? ma : mb;
            unsigned feat = ((j < 2) ? fa : fb) + (unsigned)(j & 1);
            float x = (meta & 0x80000000u) ? xs[j] : -100.0f;   // padded -> -100
            float d = x - ts[j];
            float sq = d * d;
            if (feat < D_SVG) {
                svg_acc += sq;
            } else if (feat >= D_SVG + N_TYPE) {
                unsigned k = feat - (D_SVG + N_TYPE);
                par_acc += ((meta >> k) & 1u) ? 0.0f : sq;      // replaced -> 0
            }
        }
    };

    #pragma unroll
    for (int u = 0; u < FULL_ITERS; ++u) accum(tid + u * THREADS, iv[u], tv[u]);
    if (tid < TAIL) {
        int idx = FULL_ITERS * THREADS + tid;
        accum(idx, in4p[idx], tg4p[idx]);
    }

    // --- block reduction: wave shuffle then LDS across 4 waves ---
    float vals[4] = {svg_acc, par_acc, nll_acc, cnt_acc};
    #pragma unroll
    for (int v = 0; v < 4; ++v) {
        float x = vals[v];
        #pragma unroll
        for (int off = 32; off > 0; off >>= 1) x += __shfl_down(x, off, 64);
        vals[v] = x;
    }
    const int wave = tid >> 6;
    const int lane = tid & 63;
    if (lane == 0) {
        #pragma unroll
        for (int v = 0; v < 4; ++v) sred[wave][v] = vals[v];
    }
    __syncthreads();
    if (tid == 0) {
        float s0 = sred[0][0] + sred[1][0] + sred[2][0] + sred[3][0];
        float s1 = sred[0][1] + sred[1][1] + sred[2][1] + sred[3][1];
        float s2 = sred[0][2] + sred[1][2] + sred[2][2] + sred[3][2];
        float s3 = sred[0][3] + sred[1][3] + sred[2][3] + sred[3][3];
        part[blockIdx.x] = make_float4(s0, s1, s2, s3);
    }
}

__global__ __launch_bounds__(256) void loss_reduce(const float4* __restrict__ part,
                                                   float* __restrict__ out, int nblocks,
                                                   double inv_svg_n, double inv_par_n) {
    __shared__ double sred[4][4];
    const int tid = threadIdx.x;
    double sv = 0.0, pa = 0.0, nl = 0.0, ct = 0.0;
    for (int i = tid; i < nblocks; i += 256) {
        float4 v = part[i];
        sv += v.x; pa += v.y; nl += v.z; ct += v.w;
    }
    double vals[4] = {sv, pa, nl, ct};
    #pragma unroll
    for (int v = 0; v < 4; ++v) {
        double x = vals[v];
        #pragma unroll
        for (int off = 32; off > 0; off >>= 1) x += __shfl_down(x, off, 64);
        vals[v] = x;
    }
    const int wave = tid >> 6;
    const int lane = tid & 63;
    if (lane == 0) {
        #pragma unroll
        for (int v = 0; v < 4; ++v) sred[wave][v] = vals[v];
    }
    __syncthreads();
    if (tid == 0) {
        double svg = sred[0][0] + sred[1][0] + sred[2][0] + sred[3][0];
        double par = sred[0][1] + sred[1][1] + sred[2][1] + sred[3][1];
        double nll = sred[0][2] + sred[1][2] + sred[2][2] + sred[3][2];
        double cnt = sred[0][3] + sred[1][3] + sred[2][3] + sred[3][3];
        double loss = 10.0 * svg * inv_svg_n
                    + 0.1 * nll / fmax(cnt, 1.0)
                    + 1.0 * par * inv_par_n;
        out[0] = (float)loss;
    }
}

extern "C" void kernel_launch(void* const* d_in, const int* in_sizes, int n_in,
                              void* d_out, int out_size, void* d_ws, size_t ws_size,
                              hipStream_t stream) {
    const float* input  = (const float*)d_in[0];
    const float* target = (const float*)d_in[1];
    // d_in[2] (padding mask) unused: padded <=> target[row*278+256] == -1.0f
    float*  out  = (float*)d_out;
    float4* part = (float4*)d_ws;

    const int nrows = in_sizes[0] / F_TOT;      // B*S = 131072 (divisible by 32)
    const int blocks = nrows / ROWS_PER_BLOCK;  // 4096

    loss_main<<<blocks, THREADS, 0, stream>>>(input, target, part, nrows);
    loss_reduce<<<1, 256, 0, stream>>>(part, out, blocks,
                                       1.0 / ((double)nrows * D_SVG),
                                       1.0 / ((double)nrows * N_PAR));
}

// Round 4
// 299.900 us; speedup vs baseline: 1.4689x; 1.0568x over previous
//
#include <hip/hip_runtime.h>
#include <hip/hip_bf16.h>
#include <math.h>

// Problem constants (from reference)
#define D_SVG 256
#define N_TYPE 10
#define N_PAR 12
#define F_TOT (D_SVG + N_TYPE + N_PAR)        // 278
#define ROWS_PER_BLOCK 32
#define THREADS 256
#define N4_PER_BLOCK (ROWS_PER_BLOCK * F_TOT / 4)   // 2224 float4 per chunk
#define FULL_ITERS (N4_PER_BLOCK / THREADS)         // 8
#define TAIL (N4_PER_BLOCK - FULL_ITERS * THREADS)  // 176

// ws layout:
//   float4 part_b[4096]   @ 0       (x=svg_sq_valid, y=par12_sq_valid)
//   float4 part_a[512]    @ 65536   (x=nll, y=cnt, z=par_corr)
//   unsigned bitmap[4096] @ 73728   (bit r = row 32*w+r valid)

// ---------------- Kernel A: per-row metadata, CE, par correction ----------------
__global__ __launch_bounds__(THREADS) void meta_kernel(const float* __restrict__ input,
                                                       const float* __restrict__ target,
                                                       float4* __restrict__ part_a,
                                                       unsigned* __restrict__ bitmap) {
    __shared__ float sred[4][3];
    const int tid = threadIdx.x;
    const int r = blockIdx.x * THREADS + tid;          // one row per thread

    const float2* __restrict__ tg2 = (const float2*)target;
    const float2* __restrict__ in2 = (const float2*)input;
    const long b2 = ((long)r * F_TOT + D_SVG) >> 1;    // float2 idx of type section

    float nll = 0.0f, cnt = 0.0f, corr = 0.0f;
    float2 t01 = tg2[b2];
    const bool valid = (t01.x != -1.0f);
    if (valid) {
        float tt[N_TYPE], l[N_TYPE];
        tt[0] = t01.x; tt[1] = t01.y;
        #pragma unroll
        for (int j = 1; j < 5; ++j) { float2 v = tg2[b2 + j]; tt[2*j] = v.x; tt[2*j+1] = v.y; }
        #pragma unroll
        for (int j = 0; j < 5; ++j) { float2 v = in2[b2 + j]; l[2*j] = v.x; l[2*j+1] = v.y; }
        int ti = 0; float best = tt[0];
        #pragma unroll
        for (int j = 1; j < N_TYPE; ++j) { if (tt[j] > best) { best = tt[j]; ti = j; } }
        float m = l[0];
        #pragma unroll
        for (int j = 1; j < N_TYPE; ++j) m = fmaxf(m, l[j]);
        float s = 0.0f;
        #pragma unroll
        for (int j = 0; j < N_TYPE; ++j) s += __expf(l[j] - m);
        nll = __logf(s) + m - l[ti];
        cnt = 1.0f;
        // replaced params {ti, ti+1, ti+2} (ti<=9, no wrap): they contribute 0 in the
        // reference; bulk kernel sums (x-t)^2 over all 12, so record the subtraction.
        const long p = (long)r * F_TOT + (D_SVG + N_TYPE) + ti;
        float d0 = input[p]     - target[p];
        float d1 = input[p + 1] - target[p + 1];
        float d2 = input[p + 2] - target[p + 2];
        corr = d0 * d0 + d1 * d1 + d2 * d2;
    }

    // valid bitmap: one uint32 per 32 consecutive rows
    unsigned long long bal = __ballot(valid);
    const int lane = tid & 63, wv = tid >> 6;
    if (lane == 0)  bitmap[blockIdx.x * 8 + wv * 2]     = (unsigned)bal;
    if (lane == 32) bitmap[blockIdx.x * 8 + wv * 2 + 1] = (unsigned)(bal >> 32);

    // block reduce (nll, cnt, corr)
    float vals[3] = {nll, cnt, corr};
    #pragma unroll
    for (int v = 0; v < 3; ++v) {
        float x = vals[v];
        #pragma unroll
        for (int off = 32; off > 0; off >>= 1) x += __shfl_down(x, off, 64);
        vals[v] = x;
    }
    if (lane == 0) {
        #pragma unroll
        for (int v = 0; v < 3; ++v) sred[wv][v] = vals[v];
    }
    __syncthreads();
    if (tid == 0) {
        float s0 = sred[0][0] + sred[1][0] + sred[2][0] + sred[3][0];
        float s1 = sred[0][1] + sred[1][1] + sred[2][1] + sred[3][1];
        float s2 = sred[0][2] + sred[1][2] + sred[2][2] + sred[3][2];
        part_a[blockIdx.x] = make_float4(s0, s1, s2, 0.0f);
    }
}

// ---------------- Kernel B: pure-streaming masked MSE ----------------
__global__ __launch_bounds__(THREADS) void bulk_kernel(const float* __restrict__ input,
                                                       const float* __restrict__ target,
                                                       const unsigned* __restrict__ bitmap,
                                                       float4* __restrict__ part_b) {
    __shared__ float sred[4][2];
    const int tid = threadIdx.x;
    const unsigned bits = bitmap[blockIdx.x];          // wave-uniform -> s_load

    if (bits == 0u) {                                  // all 32 rows padded:
        // contribution handled in closed form at the final reduce via npad
        if (tid == 0) part_b[blockIdx.x] = make_float4(0.f, 0.f, 0.f, 0.f);
        return;
    }

    const long row0 = (long)blockIdx.x * ROWS_PER_BLOCK;
    const float4* __restrict__ in4p = (const float4*)(input + row0 * F_TOT);
    const float4* __restrict__ tg4p = (const float4*)(target + row0 * F_TOT);

    float svg_acc = 0.0f, par_acc = 0.0f;

    // 278 % 4 == 2: a float4 crosses a row boundary only between elems 1|2.
    auto accum = [&](unsigned idx, float4 ivv, float4 tvv) {
        unsigned e0 = idx * 4u;
        unsigned ra = e0 / (unsigned)F_TOT;            // compiler magic-mul
        unsigned rb = (e0 + 2u) / (unsigned)F_TOT;
        unsigned fa = e0 - ra * (unsigned)F_TOT;
        unsigned fb = (e0 + 2u) - rb * (unsigned)F_TOT;
        unsigned vA = (bits >> ra) & 1u;
        unsigned vB = (bits >> rb) & 1u;
        float xs[4] = {ivv.x, ivv.y, ivv.z, ivv.w};
        float ts[4] = {tvv.x, tvv.y, tvv.z, tvv.w};
        #pragma unroll
        for (int j = 0; j < 4; ++j) {
            unsigned v    = (j < 2) ? vA : vB;
            unsigned feat = ((j < 2) ? fa : fb) + (unsigned)(j & 1);
            float d = xs[j] - ts[j];
            float sq = d * d;
            svg_acc += (v && feat < D_SVG) ? sq : 0.0f;
            par_acc += (v && feat >= D_SVG + N_TYPE) ? sq : 0.0f;
        }
    };

    float4 iv[FULL_ITERS], tv[FULL_ITERS];
    #pragma unroll
    for (int u = 0; u < FULL_ITERS; ++u) iv[u] = in4p[tid + u * THREADS];
    #pragma unroll
    for (int u = 0; u < FULL_ITERS; ++u) tv[u] = tg4p[tid + u * THREADS];
    #pragma unroll
    for (int u = 0; u < FULL_ITERS; ++u) accum(tid + u * THREADS, iv[u], tv[u]);
    if (tid < TAIL) {
        unsigned idx = FULL_ITERS * THREADS + tid;
        accum(idx, in4p[idx], tg4p[idx]);
    }

    // block reduce (svg, par)
    float vals[2] = {svg_acc, par_acc};
    #pragma unroll
    for (int v = 0; v < 2; ++v) {
        float x = vals[v];
        #pragma unroll
        for (int off = 32; off > 0; off >>= 1) x += __shfl_down(x, off, 64);
        vals[v] = x;
    }
    const int wave = tid >> 6, lane = tid & 63;
    if (lane == 0) { sred[wave][0] = vals[0]; sred[wave][1] = vals[1]; }
    __syncthreads();
    if (tid == 0) {
        float s0 = sred[0][0] + sred[1][0] + sred[2][0] + sred[3][0];
        float s1 = sred[0][1] + sred[1][1] + sred[2][1] + sred[3][1];
        part_b[blockIdx.x] = make_float4(s0, s1, 0.0f, 0.0f);
    }
}

// ---------------- Final reduce + loss composition ----------------
__global__ __launch_bounds__(256) void loss_final(const float4* __restrict__ part_b,
                                                  const float4* __restrict__ part_a,
                                                  float* __restrict__ out,
                                                  int nb, int na, int nrows) {
    __shared__ double sred[4][5];
    const int tid = threadIdx.x;
    double svg = 0.0, par = 0.0, nll = 0.0, cnt = 0.0, corr = 0.0;
    for (int i = tid; i < nb; i += 256) {
        float4 v = part_b[i];
        svg += v.x; par += v.y;
    }
    for (int i = tid; i < na; i += 256) {
        float4 v = part_a[i];
        nll += v.x; cnt += v.y; corr += v.z;
    }
    double vals[5] = {svg, par, nll, cnt, corr};
    #pragma unroll
    for (int v = 0; v < 5; ++v) {
        double x = vals[v];
        #pragma unroll
        for (int off = 32; off > 0; off >>= 1) x += __shfl_down(x, off, 64);
        vals[v] = x;
    }
    const int wave = tid >> 6, lane = tid & 63;
    if (lane == 0) {
        #pragma unroll
        for (int v = 0; v < 5; ++v) sred[wave][v] = vals[v];
    }
    __syncthreads();
    if (tid == 0) {
        double S[5];
        #pragma unroll
        for (int v = 0; v < 5; ++v)
            S[v] = sred[0][v] + sred[1][v] + sred[2][v] + sred[3][v];
        double npad = (double)nrows - S[3];
        // padded rows: every svg/par element contributes (-100-(-1))^2 = 9801
        double svg_t = S[0] + 9801.0 * D_SVG * npad;
        double par_t = S[1] - S[4] + 9801.0 * N_PAR * npad;
        double loss = 10.0 * svg_t / ((double)nrows * D_SVG)
                    + 0.1  * S[2] / fmax(S[3], 1.0)
                    + 1.0  * par_t / ((double)nrows * N_PAR);
        out[0] = (float)loss;
    }
}

extern "C" void kernel_launch(void* const* d_in, const int* in_sizes, int n_in,
                              void* d_out, int out_size, void* d_ws, size_t ws_size,
                              hipStream_t stream) {
    const float* input  = (const float*)d_in[0];
    const float* target = (const float*)d_in[1];
    // d_in[2] (padding mask) unused: padded <=> target[row*278+256] == -1.0f
    float* out = (float*)d_out;

    const int nrows  = in_sizes[0] / F_TOT;     // 131072 (divisible by 256)
    const int blk_b  = nrows / ROWS_PER_BLOCK;  // 4096
    const int blk_a  = nrows / THREADS;         // 512

    float4*   part_b = (float4*)d_ws;
    float4*   part_a = (float4*)((char*)d_ws + (size_t)blk_b * sizeof(float4));
    unsigned* bitmap = (unsigned*)((char*)part_a + (size_t)blk_a * sizeof(float4));

    meta_kernel<<<blk_a, THREADS, 0, stream>>>(input, target, part_a, bitmap);
    bulk_kernel<<<blk_b, THREADS, 0, stream>>>(input, target, bitmap, part_b);
    loss_final<<<1, 256, 0, stream>>>(part_b, part_a, out, blk_b, blk_a, nrows);
}